// Round 8
// baseline (2338.134 us; speedup 1.0000x reference)
//
#include <hip/hip_runtime.h>
#include <hip/hip_bf16.h>
#include <cmath>

#define B_   2
#define S_   4096
#define D_   768
#define H_   12
#define HD_  64
#define W_   256
#define G_   64
#define DFF_ 3072
#define NB_  16      // S_/W_

typedef __hip_bfloat16 bf16;
using short8 = __attribute__((ext_vector_type(8))) short;
using f32x4  = __attribute__((ext_vector_type(4))) float;

__device__ __forceinline__ float b2f(bf16 v){ return __bfloat162float(v); }
__device__ __forceinline__ bf16  f2b(float v){ return __float2bfloat16(v); }
__device__ __forceinline__ short bfbits(float v){
    bf16 t = __float2bfloat16(v);
    return *reinterpret_cast<short*>(&t);
}
// generic load-as-float / store-from-float
__device__ __forceinline__ float ldf(const bf16* p){ return b2f(*p); }
__device__ __forceinline__ float ldf(const float* p){ return *p; }
__device__ __forceinline__ void  stc(bf16* p, float v){ *p = f2b(v); }
__device__ __forceinline__ void  stc(float* p, float v){ *p = v; }
// 8-element MFMA fragment load (bf16 direct; fp32 converted in-register)
__device__ __forceinline__ short8 load8(const bf16* p){
    return *reinterpret_cast<const short8*>(p);
}
__device__ __forceinline__ short8 load8(const float* p){
    short8 r;
    #pragma unroll
    for (int i = 0; i < 8; i++) r[i] = bfbits(p[i]);
    return r;
}

// ---------------------------------------------------------------- transpose+cvt
// dst[c*R + r] = (bf16)src[r*C + c]   (src fp32 R x C row-major)
__global__ void transpose_k(const float* __restrict__ src, bf16* __restrict__ dst,
                            int R, int C)
{
    int i = blockIdx.x * 256 + threadIdx.x;
    if (i < R * C) {
        int r = i / C, c = i % C;
        dst[(size_t)c * R + r] = f2b(src[i]);
    }
}

// ---------------------------------------------------------------- GEMM (MFMA)
// C[M,N] = A[M,K] * B[K,N] + bias.  BT is N x K row-major bf16.
// A is fp32 or bf16 (AT); C is fp32 or bf16 (OT). Bias fp32.
// Block = 256 thr = 4 waves (2x2), block tile 128x128, wave tile 64x64,
// mfma_f32_16x16x32_bf16, direct-from-global fragment loads.
template<typename AT, typename OT, bool GELU>
__global__ __launch_bounds__(256) void gemm_bias_k(const AT* __restrict__ A,
    const bf16* __restrict__ BT, const float* __restrict__ bias,
    OT* __restrict__ C, int M, int N, int K)
{
    const int lane = threadIdx.x & 63;
    const int wave = threadIdx.x >> 6;
    const int wr = wave >> 1, wc = wave & 1;
    const int row0 = blockIdx.x * 128 + wr * 64;
    const int col0 = blockIdx.y * 128 + wc * 64;
    const int lm = lane & 15;
    const int lk = (lane >> 4) * 8;

    f32x4 acc[4][4];
    #pragma unroll
    for (int i = 0; i < 4; i++)
        #pragma unroll
        for (int j = 0; j < 4; j++)
            #pragma unroll
            for (int r = 0; r < 4; r++) acc[i][j][r] = 0.f;

    const AT*   Ap = A  + (size_t)(row0 + lm) * K + lk;
    const bf16* Bp = BT + (size_t)(col0 + lm) * K + lk;

    for (int k0 = 0; k0 < K; k0 += 32) {
        short8 af[4], bf[4];
        #pragma unroll
        for (int i = 0; i < 4; i++) {
            af[i] = load8(Ap + (size_t)i * 16 * K + k0);
            bf[i] = load8(Bp + (size_t)i * 16 * K + k0);
        }
        #pragma unroll
        for (int mi = 0; mi < 4; mi++)
            #pragma unroll
            for (int ni = 0; ni < 4; ni++)
                acc[mi][ni] = __builtin_amdgcn_mfma_f32_16x16x32_bf16(
                                  af[mi], bf[ni], acc[mi][ni], 0, 0, 0);
    }

    const int rbase = row0 + (lane >> 4) * 4;
    #pragma unroll
    for (int ni = 0; ni < 4; ni++) {
        const int col = col0 + ni * 16 + lm;
        const float bv = bias[col];
        #pragma unroll
        for (int mi = 0; mi < 4; mi++) {
            #pragma unroll
            for (int r = 0; r < 4; r++) {
                const int row = rbase + mi * 16 + r;
                float v = acc[mi][ni][r] + bv;
                if (GELU) v = 0.5f * v * (1.f + erff(v * 0.70710678f));
                stc(&C[(size_t)row * N + col], v);
            }
        }
    }
}

// ---------------------------------------------------------------- qg (tiny GEMM)
// QG[b][g][col] = x[b][g] . WT[col] + bqg[col], g < G_. x fp32, WT bf16.
__global__ void qg_gemm_k(const float* __restrict__ x, const bf16* __restrict__ WT,
                          const float* __restrict__ bias, bf16* __restrict__ QG)
{
    int i = blockIdx.x * 256 + threadIdx.x;
    if (i >= B_ * G_ * D_) return;
    int col = i % D_;
    int g   = (i / D_) % G_;
    int b   = i / (D_ * G_);
    const float* xr = x  + ((size_t)b * S_ + g) * D_;
    const bf16*  wr = WT + (size_t)col * D_;
    float acc = 0.f;
    for (int k = 0; k < D_; k++) acc += __bfloat162float(f2b(xr[k])) * b2f(wr[k]);
    QG[i] = f2b(acc + bias[col]);
}

// ---------------------------------------------------------------- band attention
// One block per (b,h,n); thread t = query row t of the W_-block.
// Keys: idx<3W -> band key kr=(n-1)*W+idx (valid iff t<=idx<=t+2W, G<=kr<S, mask)
//       idx>=3W -> global key kr=idx-3W (<G), masked by mask[kr].
// NOTE: ATT aliases Qb (in-place). Each thread reads its own Q row into registers
// before the first barrier; writes after the last barrier; blocks touch disjoint
// (row-range, head-column) regions.
#define CH_ 16
__global__ __launch_bounds__(256) void band_attn_k(const bf16* Qb,
    const bf16* __restrict__ Kb, const bf16* __restrict__ Vb,
    const int* __restrict__ amask, bf16* ATT)
{
    __shared__ float Ks[CH_][HD_];
    __shared__ float Vs[CH_][HD_];
    const int n = blockIdx.x % NB_;
    const int h = (blockIdx.x / NB_) % H_;
    const int b = blockIdx.x / (NB_ * H_);
    const int t = threadIdx.x;
    const int sq = n * W_ + t;

    const bf16* qrow = Qb + ((size_t)b * S_ + sq) * D_ + h * HD_;
    float qv[HD_];
    #pragma unroll
    for (int d = 0; d < HD_; d++) qv[d] = b2f(qrow[d]);

    float outv[HD_];
    #pragma unroll
    for (int d = 0; d < HD_; d++) outv[d] = 0.f;
    float m = -1e30f, l = 0.f;

    const int NKEY = 3 * W_ + G_;   // 832
    for (int c0 = 0; c0 < NKEY; c0 += CH_) {
        __syncthreads();
        for (int e = t; e < CH_ * HD_; e += 256) {
            const int r = e >> 6, d = e & 63;
            const int idx = c0 + r;
            const int kr = (idx < 3 * W_) ? ((n - 1) * W_ + idx) : (idx - 3 * W_);
            float kvv = 0.f, vvv = 0.f;
            if (kr >= 0 && kr < S_) {
                const size_t base = ((size_t)b * S_ + kr) * D_ + h * HD_ + d;
                kvv = b2f(Kb[base]);
                vvv = b2f(Vb[base]);
            }
            Ks[r][d] = kvv; Vs[r][d] = vvv;
        }
        __syncthreads();

        float sc[CH_];
        float cmax = -1e30f;
        #pragma unroll
        for (int kk = 0; kk < CH_; kk++) {
            const int idx = c0 + kk;
            float s = 0.f;
            #pragma unroll
            for (int d = 0; d < HD_; d++) s += qv[d] * Ks[kk][d];
            s *= 0.125f;
            bool valid;
            if (idx < 3 * W_) {
                const int kr = (n - 1) * W_ + idx;
                const int krc = kr < 0 ? 0 : (kr > S_ - 1 ? S_ - 1 : kr);
                valid = (idx >= t) && (idx <= t + 2 * W_) && (kr >= G_) && (kr < S_)
                        && (amask[b * S_ + krc] > 0);
            } else {
                valid = (amask[b * S_ + (idx - 3 * W_)] > 0);
            }
            sc[kk] = valid ? s : -1e9f;
            cmax = fmaxf(cmax, sc[kk]);
        }
        const float mn = fmaxf(m, cmax);
        const float corr = __expf(m - mn);
        l *= corr;
        #pragma unroll
        for (int d = 0; d < HD_; d++) outv[d] *= corr;
        #pragma unroll
        for (int kk = 0; kk < CH_; kk++) {
            const float p = __expf(sc[kk] - mn);
            l += p;
            #pragma unroll
            for (int d = 0; d < HD_; d++) outv[d] += p * Vs[kk][d];
        }
        m = mn;
    }
    const float inv = 1.f / l;
    bf16* orow = ATT + ((size_t)b * S_ + sq) * D_ + h * HD_;
    #pragma unroll
    for (int d = 0; d < HD_; d++) orow[d] = f2b(outv[d] * inv);
}

// ---------------------------------------------------------------- global attention
// One block per (b,h,g). Scores over full S in LDS, then P.Vg.
__global__ __launch_bounds__(256) void global_attn_k(const bf16* __restrict__ QG,
    const bf16* __restrict__ KG, const bf16* __restrict__ VG,
    const int* __restrict__ amask, bf16* __restrict__ ATT)
{
    __shared__ float sc[S_];
    __shared__ float red[256];
    __shared__ float qv[HD_];
    const int g = blockIdx.x % G_;
    const int h = (blockIdx.x / G_) % H_;
    const int b = blockIdx.x / (G_ * H_);
    const int t = threadIdx.x;

    if (t < HD_) qv[t] = b2f(QG[((size_t)b * G_ + g) * D_ + h * HD_ + t]);
    __syncthreads();

    float lmax = -1e30f;
    for (int s = t; s < S_; s += 256) {
        const bf16* krow = KG + ((size_t)b * S_ + s) * D_ + h * HD_;
        float acc = 0.f;
        #pragma unroll
        for (int d = 0; d < HD_; d++) acc += qv[d] * b2f(krow[d]);
        acc *= 0.125f;
        if (amask[b * S_ + s] <= 0) acc = -1e9f;
        sc[s] = acc;
        lmax = fmaxf(lmax, acc);
    }
    red[t] = lmax; __syncthreads();
    for (int st = 128; st > 0; st >>= 1) {
        if (t < st) red[t] = fmaxf(red[t], red[t + st]);
        __syncthreads();
    }
    const float mm = red[0];
    __syncthreads();

    float lsum = 0.f;
    for (int s = t; s < S_; s += 256) {
        const float p = __expf(sc[s] - mm);
        sc[s] = p;
        lsum += p;
    }
    red[t] = lsum; __syncthreads();
    for (int st = 128; st > 0; st >>= 1) {
        if (t < st) red[t] += red[t + st];
        __syncthreads();
    }
    const float inv = 1.f / red[0];
    __syncthreads();

    const int d = t & 63, c = t >> 6;
    float part = 0.f;
    for (int s = c * 1024; s < (c + 1) * 1024; s++)
        part += sc[s] * b2f(VG[((size_t)b * S_ + s) * D_ + h * HD_ + d]);
    red[t] = part;
    __syncthreads();
    if (t < HD_) {
        const float o = (red[t] + red[t + 64] + red[t + 128] + red[t + 192]) * inv;
        ATT[((size_t)b * S_ + g) * D_ + h * HD_ + t] = f2b(o);
    }
}

// ---------------------------------------------------------------- add + layernorm
// out[row] = LN(A[row] + Bv[row]) * gamma + beta. Templated dtypes; out may
// alias A or Bv in-place (each thread reads its 3 elems before any write).
template<typename TA, typename TB, typename TO>
__global__ __launch_bounds__(256) void add_ln_k(const TA* A,
    const TB* Bv, const float* __restrict__ gamma,
    const float* __restrict__ beta, TO* out)
{
    __shared__ float red[256];
    const int row = blockIdx.x;
    const int t = threadIdx.x;
    const TA* ar = A  + (size_t)row * D_;
    const TB* br = Bv + (size_t)row * D_;
    float v[3];
    float s = 0.f;
    #pragma unroll
    for (int i = 0; i < 3; i++) {
        v[i] = ldf(ar + t + i * 256) + ldf(br + t + i * 256);
        s += v[i];
    }
    red[t] = s; __syncthreads();
    for (int st = 128; st > 0; st >>= 1) {
        if (t < st) red[t] += red[t + st];
        __syncthreads();
    }
    const float mu = red[0] / D_;
    __syncthreads();
    float s2 = 0.f;
    #pragma unroll
    for (int i = 0; i < 3; i++) { const float dd = v[i] - mu; s2 += dd * dd; }
    red[t] = s2; __syncthreads();
    for (int st = 128; st > 0; st >>= 1) {
        if (t < st) red[t] += red[t + st];
        __syncthreads();
    }
    const float rstd = rsqrtf(red[0] / D_ + 1e-5f);
    #pragma unroll
    for (int i = 0; i < 3; i++) {
        const int c = t + i * 256;
        stc(&out[(size_t)row * D_ + c], (v[i] - mu) * rstd * gamma[c] + beta[c]);
    }
}

// ---------------------------------------------------------------- launch
// I/O is fp32 (per reference dtypes); internals bf16 for MFMA.
// ws (bf16 el): WT (D*DFF = 2,359,296) + QG (98,304) + P0 + P1 [+ P2] (BSD each).
// Min (quarters): 15,040,512 el = 30.1 MB; halves mode needs 42.7 MB.
// d_out (fp32, 25.2 MB) doubles as ONE bf16 BSD scratch slot (V, then VG)
// before its fp32 life begins (FF2 output + final LN, in-place).
extern "C" void kernel_launch(void* const* d_in, const int* in_sizes, int n_in,
                              void* d_out, int out_size, void* d_ws, size_t ws_size,
                              hipStream_t stream)
{
    (void)in_sizes; (void)n_in; (void)out_size;
    const float* x    = (const float*)d_in[0];
    const float* Wq   = (const float*)d_in[1];
    const float* bq   = (const float*)d_in[2];
    const float* Wk   = (const float*)d_in[3];
    const float* bk   = (const float*)d_in[4];
    const float* Wv   = (const float*)d_in[5];
    const float* bv   = (const float*)d_in[6];
    const float* Wqg  = (const float*)d_in[7];
    const float* bqg  = (const float*)d_in[8];
    const float* Wkg  = (const float*)d_in[9];
    const float* bkg  = (const float*)d_in[10];
    const float* Wvg  = (const float*)d_in[11];
    const float* bvg  = (const float*)d_in[12];
    const float* Wo   = (const float*)d_in[13];
    const float* bo   = (const float*)d_in[14];
    const float* ln1g = (const float*)d_in[15];
    const float* ln1b = (const float*)d_in[16];
    const float* Wf1  = (const float*)d_in[17];
    const float* bf1  = (const float*)d_in[18];
    const float* Wf2  = (const float*)d_in[19];
    const float* bf2  = (const float*)d_in[20];
    const float* ln2g = (const float*)d_in[21];
    const float* ln2b = (const float*)d_in[22];
    const int*   am   = (const int*)d_in[23];

    const size_t WDF = (size_t)D_ * DFF_;      // 2,359,296
    const size_t BSD = (size_t)B_ * S_ * D_;   // 6,291,456
    bf16*  ws   = (bf16*)d_ws;
    bf16*  WT   = ws;                // transpose+cvt scratch (reused)
    bf16*  QG   = WT + WDF;
    bf16*  P0   = QG + (size_t)B_ * G_ * D_;
    bf16*  P1   = P0 + BSD;
    bf16*  OUTb = (bf16*)d_out;      // bf16 scratch life: V, then VG
    float* OUTf = (float*)d_out;     // fp32 life: FF2 out + final LN

    // FF split: halves need FF1 chunk = 2 BSD (P1+P2); quarters need 1 (P1).
    const size_t need_halves = (WDF + (size_t)B_ * G_ * D_ + 3 * BSD) * sizeof(bf16);
    const int nchunk = (ws_size >= need_halves) ? 2 : 4;

    const int tpb = 256;
    const int M  = B_ * S_;                       // 8192
    const int nT  = (int)(((size_t)D_ * D_ + 255) / 256);
    const int nTf = (int)((WDF + 255) / 256);
    dim3 gP(M / 128, D_ / 128);                   // (64, 6)

    // --- projections (x fp32 read directly; WT reused sequentially) ---
    transpose_k<<<nT, tpb, 0, stream>>>(Wq, WT, D_, D_);
    gemm_bias_k<float, bf16, false><<<gP, tpb, 0, stream>>>(x, WT, bq, P0, M, D_, D_);   // Q
    transpose_k<<<nT, tpb, 0, stream>>>(Wk, WT, D_, D_);
    gemm_bias_k<float, bf16, false><<<gP, tpb, 0, stream>>>(x, WT, bk, P1, M, D_, D_);   // K
    transpose_k<<<nT, tpb, 0, stream>>>(Wv, WT, D_, D_);
    gemm_bias_k<float, bf16, false><<<gP, tpb, 0, stream>>>(x, WT, bv, OUTb, M, D_, D_); // V
    transpose_k<<<nT, tpb, 0, stream>>>(Wqg, WT, D_, D_);
    qg_gemm_k<<<(B_ * G_ * D_ + 255) / 256, tpb, 0, stream>>>(x, WT, bqg, QG);

    // --- band attention: ATT overwrites Q (P0) in place ---
    band_attn_k<<<B_ * H_ * NB_, tpb, 0, stream>>>(P0, P1, OUTb, am, P0);

    // --- global K/V projections reuse K/V slots ---
    transpose_k<<<nT, tpb, 0, stream>>>(Wkg, WT, D_, D_);
    gemm_bias_k<float, bf16, false><<<gP, tpb, 0, stream>>>(x, WT, bkg, P1, M, D_, D_);  // KG
    transpose_k<<<nT, tpb, 0, stream>>>(Wvg, WT, D_, D_);
    gemm_bias_k<float, bf16, false><<<gP, tpb, 0, stream>>>(x, WT, bvg, OUTb, M, D_, D_);// VG
    global_attn_k<<<B_ * H_ * G_, tpb, 0, stream>>>(QG, P1, OUTb, am, P0);

    // --- output projection + LN1 ---
    transpose_k<<<nT, tpb, 0, stream>>>(Wo, WT, D_, D_);
    gemm_bias_k<bf16, bf16, false><<<gP, tpb, 0, stream>>>(P0, WT, bo, P1, M, D_, D_);   // APRJ
    add_ln_k<float, bf16, bf16><<<M, tpb, 0, stream>>>(x, P1, ln1g, ln1b, P0);           // H1

    // --- FF block in M-chunks; FF1 chunk -> P1(+P2), FF2 -> d_out fp32 ---
    const int Mc = M / nchunk;                    // 4096 or 2048
    dim3 gF1(Mc / 128, DFF_ / 128);
    dim3 gF2(Mc / 128, D_ / 128);
    for (int c = 0; c < nchunk; c++) {
        const size_t off = (size_t)c * Mc * D_;
        transpose_k<<<nTf, tpb, 0, stream>>>(Wf1, WT, D_, DFF_);
        gemm_bias_k<bf16, bf16, true ><<<gF1, tpb, 0, stream>>>(P0 + off, WT, bf1, P1,
                                                                Mc, DFF_, D_);
        transpose_k<<<nTf, tpb, 0, stream>>>(Wf2, WT, DFF_, D_);
        gemm_bias_k<bf16, float, false><<<gF2, tpb, 0, stream>>>(P1, WT, bf2, OUTf + off,
                                                                 Mc, D_, DFF_);
    }
    // --- final residual LN, in place on d_out (fp32) ---
    add_ln_k<bf16, float, float><<<M, tpb, 0, stream>>>(P0, OUTf, ln2g, ln2b, OUTf);
}